// Round 6
// baseline (537.073 us; speedup 1.0000x reference)
//
#include <hip/hip_runtime.h>
#include <cstdint>

// Hierarchical classification head, R14:
//   cast         : fp32 -> fp8 e4m3 X and W (W pre-scaled x16), bias fp32;
//                  zeroes the last-block ticket counter.
//   gemm_sig     : Zb = sigmoid((Xq @ Wq^T)/16 + b) bf16; fp8 MFMA 16x16x32.
//                  NEW (R14): 128x128 tile (ladder m93/m103: tile 64->128 was
//                  the single biggest lever), wave = 64x64 (acc[4][4]),
//                  BK=64 double-buffered with R13's counted-vmcnt protocol
//                  (vmcnt(4): next tile's 4 loads stay in flight across both
//                  barriers). 128 MFMA between barrier pairs (2x R13).
//                  LDS 2x(8+8) KB = 32 KB -> 5 blocks/CU fit; grid 800 =
//                  8 XCDs x 100 (bijective band swizzle), all resident.
//                  16B-rotation swizzle kept: A/B staging are identical
//                  128-row clones of the verified R8/R13 B-staging.
//   logits_loss  : per-row logits3 -> d_out (R8, measured good) + NEW:
//                  last-block-ticket fold of the final mean-loss reduce
//                  (removes the 1-block final_reduce launch, ~4 us).

typedef unsigned short u16;
typedef unsigned char u8;
typedef long i64;
typedef float f32x4 __attribute__((ext_vector_type(4)));

#define AS_G __attribute__((address_space(1)))
#define AS_L __attribute__((address_space(3)))

constexpr int BATCH = 4096;
constexpr int H     = 1024;
constexpr int N1 = 28, N2 = 280, N3 = 2800;
constexpr int NT = N1 + N2 + N3;   // 3108
constexpr int NP = 3200;           // 25 * 128
constexpr int NANC = N1 + N2 + 280;  // 588 ancestor values
constexpr float WSCALE = 16.0f;
constexpr float WINV   = 1.0f / 16.0f;

__device__ inline u16 f2bf(float f) {
    unsigned int u = __float_as_uint(f);
    u += 0x7fffu + ((u >> 16) & 1u);
    return (u16)(u >> 16);
}
__device__ inline float bf2f(unsigned int u) { return __uint_as_float(u << 16); }

__device__ inline unsigned int pk4_fp8(float a, float b, float c, float d) {
    unsigned int r = __builtin_amdgcn_cvt_pk_fp8_f32(a, b, 0, false);
    r = __builtin_amdgcn_cvt_pk_fp8_f32(c, d, (int)r, true);
    return r;
}

// ---------------- cast fp32 -> fp8 + fused bias ----------------
constexpr int XG = (BATCH * H) / 4;   // 1,048,576
constexpr int WG = (NP * H) / 4;      //   819,200
constexpr int BG = NP / 4;            //       800

__global__ __launch_bounds__(256) void cast_kernel(
        const float* __restrict__ x,
        const float* __restrict__ W1, const float* __restrict__ W2,
        const float* __restrict__ W3,
        const float* __restrict__ b1, const float* __restrict__ b2,
        const float* __restrict__ b3,
        u8* __restrict__ Xq, u8* __restrict__ Wq, float* __restrict__ biasf,
        unsigned* __restrict__ counter) {
    int g = blockIdx.x * 256 + threadIdx.x;
    if (g == 0) *counter = 0u;
    if (g < XG) {
        float4 v = ((const float4*)x)[g];
        ((unsigned int*)Xq)[g] = pk4_fp8(v.x, v.y, v.z, v.w);
    } else if (g < XG + WG) {
        int wg = g - XG;
        int row = wg >> 8, cg = wg & 255;
        float4 v = make_float4(0.f, 0.f, 0.f, 0.f);
        if (row < N1)           v = ((const float4*)W1)[row * 256 + cg];
        else if (row < N1 + N2) v = ((const float4*)W2)[(row - N1) * 256 + cg];
        else if (row < NT)      v = ((const float4*)W3)[(row - N1 - N2) * 256 + cg];
        ((unsigned int*)Wq)[wg] = pk4_fp8(v.x * WSCALE, v.y * WSCALE, v.z * WSCALE, v.w * WSCALE);
    } else if (g < XG + WG + BG) {
        int bg = g - XG - WG;
        float4 v; float* vp = &v.x;
        #pragma unroll
        for (int i = 0; i < 4; ++i) {
            int c = bg * 4 + i; float t = 0.f;
            if (c < N1)           t = b1[c];
            else if (c < N1 + N2) t = b2[c - N1];
            else if (c < NT)      t = b3[c - N1 - N2];
            vp[i] = t;
        }
        ((float4*)biasf)[bg] = v;
    }
}

// ---------------- GEMM: Zb = sigmoid(acc/16 + bias), fp8 inputs, bf16 out ----------------
// 128x128 tile, BK=64 dbuf, counted vmcnt(4), 4 waves 2x2 (wave = 64x64).
// LDS 32 KB -> 5 blocks/CU fit; grid 800 (32 m-tiles x 25 n-tiles).
__global__ __launch_bounds__(256) void gemm_sig(
        const u8* __restrict__ Xq, const u8* __restrict__ Wq,
        const float* __restrict__ biasf, u16* __restrict__ Zb) {
    __shared__ __align__(16) u8 As[2][2 * 128 * 32];   // 8 KB per buffer
    __shared__ __align__(16) u8 Bs[2][2 * 128 * 32];   // 8 KB per buffer

    // XCD band swizzle: 32 m-tiles x 25 n-tiles; XCD owns a 4-m-tile band.
    // Per-XCD working set: A band 512 KB + B stream 3.2 MB < 4 MB L2.
    const int id  = blockIdx.x;        // 0..799
    const int xcd = id & 7;
    const int j   = id >> 3;           // 0..99
    const int m0 = ((xcd << 2) | (j & 3)) * 128;   // m-tile 0..31
    const int n0 = (j >> 2) * 128;                 // n-tile 0..24

    const int tid  = threadIdx.x;
    const int lane = tid & 63;
    const int wave = tid >> 6;
    const int wm = (wave >> 1) * 64;   // wave m-origin within tile
    const int wn = (wave & 1) * 64;    // wave n-origin within tile

    const int laneM = lane & 15;
    // 16B-rotation swizzle (R7): unit index = (u>>1) ^ ((row>>2)&1); valid
    // because bit2 of every fragment row (wm/wn + i*16 + laneM) == bit2 of laneM.
    const int u   = lane >> 4;
    const int xb  = (laneM >> 2) & 1;
    const int laneKb = (((u >> 1) ^ xb) << 4) + (u & 1) * 8;

    // staging (identical for A and B): 512 chunks of 16B per operand per
    // buffer -> 2 chunks/thread each. chunk c: panel=c>>8, rem=c&255,
    // row=rem>>1, v=rem&1. LDS linear [panel][row][32B]; global 16B-unit
    // rotated by row bit2 (write-side of the verified swizzle pair).
    int srow[2], sgoff[2];
    #pragma unroll
    for (int t = 0; t < 2; ++t) {
        const int c = tid + 256 * t;
        const int panel = c >> 8, rem = c & 255;
        const int row = rem >> 1, v = rem & 1;
        srow[t]  = row;
        sgoff[t] = panel * 32 + ((v ^ ((row >> 2) & 1)) << 4);
    }

    auto STAGE = [&](int bufi, int kt) {       // 4 global_load_lds / thread
        const int k0 = kt * 64;
        #pragma unroll
        for (int t = 0; t < 2; ++t) {
            const int c = tid + 256 * t;
            __builtin_amdgcn_global_load_lds(
                (const AS_G uint32_t*)(Xq + (size_t)(m0 + srow[t]) * H + k0 + sgoff[t]),
                (AS_L uint32_t*)&As[bufi][c * 16], 16, 0, 0);
            __builtin_amdgcn_global_load_lds(
                (const AS_G uint32_t*)(Wq + (size_t)(n0 + srow[t]) * H + k0 + sgoff[t]),
                (AS_L uint32_t*)&Bs[bufi][c * 16], 16, 0, 0);
        }
    };

    f32x4 acc[4][4] = {};

    STAGE(0, 0);
    int buf = 0;
    for (int kt = 0; kt < H / 64; ++kt) {          // 16 iterations
        if (kt + 1 < H / 64) {
            STAGE(buf ^ 1, kt + 1);                // next tile: stays in flight
            asm volatile("s_waitcnt vmcnt(4)" ::: "memory");   // cur tile landed
        } else {
            asm volatile("s_waitcnt vmcnt(0)" ::: "memory");
        }
        __builtin_amdgcn_s_barrier();              // all waves see cur tile
        __builtin_amdgcn_sched_barrier(0);         // pin ds_reads below (rule #18)

        #pragma unroll
        for (int p = 0; p < 2; ++p) {               // 2 k-panels of 32
            i64 af[4], bfv[4];
            #pragma unroll
            for (int i = 0; i < 4; ++i) {
                af[i]  = *(const i64*)&As[buf][p * 4096 + (wm + i * 16 + laneM) * 32 + laneKb];
                bfv[i] = *(const i64*)&Bs[buf][p * 4096 + (wn + i * 16 + laneM) * 32 + laneKb];
            }
            #pragma unroll
            for (int am = 0; am < 4; ++am)
                #pragma unroll
                for (int bn = 0; bn < 4; ++bn)
                    acc[am][bn] = __builtin_amdgcn_mfma_f32_16x16x32_fp8_fp8(
                        af[am], bfv[bn], acc[am][bn], 0, 0, 0);
        }
        __builtin_amdgcn_sched_barrier(0);         // keep reads above barrier
        __builtin_amdgcn_s_barrier();              // all reads of buf done
        buf ^= 1;
    }

    // epilogue: C/D layout col = lane&15, row = (lane>>4)*4 + r; unscale, bf16 store
    #pragma unroll
    for (int bn = 0; bn < 4; ++bn) {
        const int col = n0 + wn + bn * 16 + laneM;
        if (col >= NT) continue;
        const float bias = biasf[col];
        #pragma unroll
        for (int am = 0; am < 4; ++am) {
            const int rbase = m0 + wm + am * 16 + u * 4;
            #pragma unroll
            for (int r = 0; r < 4; ++r) {
                float v = acc[am][bn][r] * WINV + bias;
                Zb[(size_t)(rbase + r) * NP + col] = f2bf(1.0f / (1.0f + __expf(-v)));
            }
        }
    }
}

// ---------------- per-row logits + CE partial + last-block mean reduce ----------------
// LDS holds only the 588 ancestor z (z1|z2|z3[0:280)); z3[k] streamed global.
__global__ __launch_bounds__(256) void logits_loss(
        const u16* __restrict__ Zb, const int* __restrict__ labels,
        float* __restrict__ out, float* __restrict__ partials,
        unsigned* __restrict__ counter) {
    __shared__ float zs[NANC];             // [0,28) z1 | [28,308) z2 | [308,588) z3[0:280)
    __shared__ float red[12];
    __shared__ unsigned ticket_s;
    const int b = blockIdx.x, tid = threadIdx.x;
    const u16* Zrow = Zb + (size_t)b * NP;

    const unsigned int* Zr = (const unsigned int*)Zrow;
    for (int i = tid; i < NANC / 2; i += 256) {    // 294 uints
        unsigned int v = Zr[i];
        zs[2 * i]     = bf2f(v & 0xffffu);
        zs[2 * i + 1] = bf2f(v >> 16);
    }
    __syncthreads();

    float se1 = 0.f, se2 = 0.f, se3 = 0.f;
    float4* outr4 = (float4*)(out + (size_t)b * N3);
    // z3 block starts at element 308 (uint index 154, even -> uint2-aligned)
    const uint2* Z3s = (const uint2*)(Zrow + N1 + N2);
    for (int q = tid; q < N3 / 4; q += 256) {
        const uint2 zv = Z3s[q];               // z3[4q..4q+3]
        float z3v[4] = { bf2f(zv.x & 0xffffu), bf2f(zv.x >> 16),
                         bf2f(zv.y & 0xffffu), bf2f(zv.y >> 16) };
        const int k = q * 4;
        float4 o; float* op = &o.x;
        #pragma unroll
        for (int uu = 0; uu < 4; ++uu) {
            const int kk = k + uu;
            float lg = z3v[uu] * zs[308 + kk / 10] * zs[308 + kk / 100];
            op[uu] = lg;
            se3 += __expf(lg);
        }
        outr4[q] = o;
    }
    for (int jj = tid; jj < N2; jj += 256)
        se2 += __expf(zs[N1 + jj] * zs[N1 + jj / 10]);
    if (tid < N1)
        se1 = __expf(zs[tid]);

    #pragma unroll
    for (int off = 32; off > 0; off >>= 1) {
        se1 += __shfl_down(se1, off, 64);
        se2 += __shfl_down(se2, off, 64);
        se3 += __shfl_down(se3, off, 64);
    }
    if ((tid & 63) == 0) {
        int w = tid >> 6;
        red[w] = se3; red[4 + w] = se2; red[8 + w] = se1;
    }
    __syncthreads();
    if (tid == 0) {
        float s3 = red[0] + red[1] + red[2] + red[3];
        float s2 = red[4] + red[5] + red[6] + red[7];
        float s1 = red[8] + red[9] + red[10] + red[11];
        int lab  = labels[b];
        int lab2 = lab / 10, lab1 = lab / 100;
        float l1 = zs[lab1];
        float l2 = zs[N1 + lab2] * zs[N1 + lab2 / 10];
        float l3 = bf2f((unsigned int)Zrow[N1 + N2 + lab]) * zs[308 + lab2] * zs[308 + lab1];
        partials[b] = (logf(s1) - l1) + (logf(s2) - l2) + (logf(s3) - l3);
    }

    // ---- last-block ticket: fold the final mean reduce into this kernel ----
    __threadfence();                        // release partials[b]
    if (tid == 0) ticket_s = atomicAdd(counter, 1u);
    __syncthreads();
    if (ticket_s == BATCH - 1) {
        __threadfence();                    // acquire all partials
        const volatile float* vp = partials;
        float s = 0.f;
        for (int i = tid; i < BATCH; i += 256) s += vp[i];
        #pragma unroll
        for (int off = 32; off > 0; off >>= 1) s += __shfl_down(s, off, 64);
        if ((tid & 63) == 0) red[tid >> 6] = s;
        __syncthreads();
        if (tid == 0)
            out[(size_t)BATCH * N3] = (red[0] + red[1] + red[2] + red[3]) * (1.0f / BATCH);
    }
}

extern "C" void kernel_launch(void* const* d_in, const int* in_sizes, int n_in,
                              void* d_out, int out_size, void* d_ws, size_t ws_size,
                              hipStream_t stream) {
    const float* x      = (const float*)d_in[0];
    const int*   labels = (const int*)d_in[1];
    const float* W1     = (const float*)d_in[2];
    const float* b1     = (const float*)d_in[3];
    const float* W2     = (const float*)d_in[4];
    const float* b2     = (const float*)d_in[5];
    const float* W3     = (const float*)d_in[6];
    const float* b3     = (const float*)d_in[7];
    float* out = (float*)d_out;

    char* ws = (char*)d_ws;
    u8*    Xq       = (u8*)ws;                     //  4,194,304 B  [4096][1024] fp8
    u8*    Wq       = (u8*)(ws + 4194304);         //  3,276,800 B  [3200][1024] fp8
    u16*   Zb       = (u16*)(ws + 7471104);        // 26,214,400 B  [4096][3200] bf16
    float* biasf    = (float*)(ws + 33685504);     //     12,800 B
    float* partials = (float*)(ws + 33698304);     //     16,384 B
    unsigned* counter = (unsigned*)(ws + 33714688);//          4 B
    // total ws use: 33,714,692 B

    cast_kernel<<<(XG + WG + BG + 255) / 256, 256, 0, stream>>>(
        x, W1, W2, W3, b1, b2, b3, Xq, Wq, biasf, counter);
    gemm_sig<<<800, 256, 0, stream>>>(Xq, Wq, biasf, Zb);
    logits_loss<<<BATCH, 256, 0, stream>>>(Zb, labels, out, partials, counter);
}

// Round 7
// 158.042 us; speedup vs baseline: 3.3983x; 3.3983x over previous
//
#include <hip/hip_runtime.h>
#include <cstdint>

// Hierarchical classification head, R15 (= R14 gemm + R8 tail):
//   cast         : fp32 -> fp8 e4m3 X and W (W pre-scaled x16), bias fp32
//   gemm_sig     : Zb = sigmoid((Xq @ Wq^T)/16 + b) bf16; fp8 MFMA 16x16x32.
//                  128x128 tile (R14), wave = 64x64 (acc[4][4]), BK=64
//                  double-buffered, counted vmcnt(4) protocol (R13): next
//                  tile's 4 loads stay in flight across both barriers.
//                  128 MFMA between barrier pairs. LDS 32 KB -> 5 blocks/CU;
//                  grid 800 = 8 XCDs x 100 (bijective band swizzle).
//                  Inferred ~25-30 us in R14 (537 - 84 fills - 421 logits - 7 cast).
//   logits_loss  : per-row logits3 -> d_out; 588 ancestor z in LDS, z3[k]
//                  streamed (R8, measured ~14 us). R14's last-block-ticket
//                  fold REVERTED: its __threadfence() = device-scope L2
//                  writeback per block on non-coherent XCDs -> 410 us stall.
//   final_reduce : 4096 partials -> mean loss scalar (separate launch; 4 us
//                  is cheaper than any cross-XCD fence scheme).

typedef unsigned short u16;
typedef unsigned char u8;
typedef long i64;
typedef float f32x4 __attribute__((ext_vector_type(4)));

#define AS_G __attribute__((address_space(1)))
#define AS_L __attribute__((address_space(3)))

constexpr int BATCH = 4096;
constexpr int H     = 1024;
constexpr int N1 = 28, N2 = 280, N3 = 2800;
constexpr int NT = N1 + N2 + N3;   // 3108
constexpr int NP = 3200;           // 25 * 128
constexpr int NANC = N1 + N2 + 280;  // 588 ancestor values
constexpr float WSCALE = 16.0f;
constexpr float WINV   = 1.0f / 16.0f;

__device__ inline u16 f2bf(float f) {
    unsigned int u = __float_as_uint(f);
    u += 0x7fffu + ((u >> 16) & 1u);
    return (u16)(u >> 16);
}
__device__ inline float bf2f(unsigned int u) { return __uint_as_float(u << 16); }

__device__ inline unsigned int pk4_fp8(float a, float b, float c, float d) {
    unsigned int r = __builtin_amdgcn_cvt_pk_fp8_f32(a, b, 0, false);
    r = __builtin_amdgcn_cvt_pk_fp8_f32(c, d, (int)r, true);
    return r;
}

// ---------------- cast fp32 -> fp8 + fused bias ----------------
constexpr int XG = (BATCH * H) / 4;   // 1,048,576
constexpr int WG = (NP * H) / 4;      //   819,200
constexpr int BG = NP / 4;            //       800

__global__ __launch_bounds__(256) void cast_kernel(
        const float* __restrict__ x,
        const float* __restrict__ W1, const float* __restrict__ W2,
        const float* __restrict__ W3,
        const float* __restrict__ b1, const float* __restrict__ b2,
        const float* __restrict__ b3,
        u8* __restrict__ Xq, u8* __restrict__ Wq, float* __restrict__ biasf) {
    int g = blockIdx.x * 256 + threadIdx.x;
    if (g < XG) {
        float4 v = ((const float4*)x)[g];
        ((unsigned int*)Xq)[g] = pk4_fp8(v.x, v.y, v.z, v.w);
    } else if (g < XG + WG) {
        int wg = g - XG;
        int row = wg >> 8, cg = wg & 255;
        float4 v = make_float4(0.f, 0.f, 0.f, 0.f);
        if (row < N1)           v = ((const float4*)W1)[row * 256 + cg];
        else if (row < N1 + N2) v = ((const float4*)W2)[(row - N1) * 256 + cg];
        else if (row < NT)      v = ((const float4*)W3)[(row - N1 - N2) * 256 + cg];
        ((unsigned int*)Wq)[wg] = pk4_fp8(v.x * WSCALE, v.y * WSCALE, v.z * WSCALE, v.w * WSCALE);
    } else if (g < XG + WG + BG) {
        int bg = g - XG - WG;
        float4 v; float* vp = &v.x;
        #pragma unroll
        for (int i = 0; i < 4; ++i) {
            int c = bg * 4 + i; float t = 0.f;
            if (c < N1)           t = b1[c];
            else if (c < N1 + N2) t = b2[c - N1];
            else if (c < NT)      t = b3[c - N1 - N2];
            vp[i] = t;
        }
        ((float4*)biasf)[bg] = v;
    }
}

// ---------------- GEMM: Zb = sigmoid(acc/16 + bias), fp8 inputs, bf16 out ----------------
// 128x128 tile, BK=64 dbuf, counted vmcnt(4), 4 waves 2x2 (wave = 64x64).
// LDS 32 KB -> 5 blocks/CU fit; grid 800 (32 m-tiles x 25 n-tiles).
__global__ __launch_bounds__(256) void gemm_sig(
        const u8* __restrict__ Xq, const u8* __restrict__ Wq,
        const float* __restrict__ biasf, u16* __restrict__ Zb) {
    __shared__ __align__(16) u8 As[2][2 * 128 * 32];   // 8 KB per buffer
    __shared__ __align__(16) u8 Bs[2][2 * 128 * 32];   // 8 KB per buffer

    // XCD band swizzle: 32 m-tiles x 25 n-tiles; XCD owns a 4-m-tile band.
    // Per-XCD working set: A band 512 KB + B stream 3.2 MB < 4 MB L2.
    const int id  = blockIdx.x;        // 0..799
    const int xcd = id & 7;
    const int j   = id >> 3;           // 0..99
    const int m0 = ((xcd << 2) | (j & 3)) * 128;   // m-tile 0..31
    const int n0 = (j >> 2) * 128;                 // n-tile 0..24

    const int tid  = threadIdx.x;
    const int lane = tid & 63;
    const int wave = tid >> 6;
    const int wm = (wave >> 1) * 64;   // wave m-origin within tile
    const int wn = (wave & 1) * 64;    // wave n-origin within tile

    const int laneM = lane & 15;
    // 16B-rotation swizzle (R7): unit index = (u>>1) ^ ((row>>2)&1); valid
    // because bit2 of every fragment row (wm/wn + i*16 + laneM) == bit2 of laneM.
    const int u   = lane >> 4;
    const int xb  = (laneM >> 2) & 1;
    const int laneKb = (((u >> 1) ^ xb) << 4) + (u & 1) * 8;

    // staging (identical for A and B): 512 chunks of 16B per operand per
    // buffer -> 2 chunks/thread each. chunk c: panel=c>>8, rem=c&255,
    // row=rem>>1, v=rem&1. LDS linear [panel][row][32B]; global 16B-unit
    // rotated by row bit2 (write-side of the verified swizzle pair).
    int srow[2], sgoff[2];
    #pragma unroll
    for (int t = 0; t < 2; ++t) {
        const int c = tid + 256 * t;
        const int panel = c >> 8, rem = c & 255;
        const int row = rem >> 1, v = rem & 1;
        srow[t]  = row;
        sgoff[t] = panel * 32 + ((v ^ ((row >> 2) & 1)) << 4);
    }

    auto STAGE = [&](int bufi, int kt) {       // 4 global_load_lds / thread
        const int k0 = kt * 64;
        #pragma unroll
        for (int t = 0; t < 2; ++t) {
            const int c = tid + 256 * t;
            __builtin_amdgcn_global_load_lds(
                (const AS_G uint32_t*)(Xq + (size_t)(m0 + srow[t]) * H + k0 + sgoff[t]),
                (AS_L uint32_t*)&As[bufi][c * 16], 16, 0, 0);
            __builtin_amdgcn_global_load_lds(
                (const AS_G uint32_t*)(Wq + (size_t)(n0 + srow[t]) * H + k0 + sgoff[t]),
                (AS_L uint32_t*)&Bs[bufi][c * 16], 16, 0, 0);
        }
    };

    f32x4 acc[4][4] = {};

    STAGE(0, 0);
    int buf = 0;
    for (int kt = 0; kt < H / 64; ++kt) {          // 16 iterations
        if (kt + 1 < H / 64) {
            STAGE(buf ^ 1, kt + 1);                // next tile: stays in flight
            asm volatile("s_waitcnt vmcnt(4)" ::: "memory");   // cur tile landed
        } else {
            asm volatile("s_waitcnt vmcnt(0)" ::: "memory");
        }
        __builtin_amdgcn_s_barrier();              // all waves see cur tile
        __builtin_amdgcn_sched_barrier(0);         // pin ds_reads below (rule #18)

        #pragma unroll
        for (int p = 0; p < 2; ++p) {               // 2 k-panels of 32
            i64 af[4], bfv[4];
            #pragma unroll
            for (int i = 0; i < 4; ++i) {
                af[i]  = *(const i64*)&As[buf][p * 4096 + (wm + i * 16 + laneM) * 32 + laneKb];
                bfv[i] = *(const i64*)&Bs[buf][p * 4096 + (wn + i * 16 + laneM) * 32 + laneKb];
            }
            #pragma unroll
            for (int am = 0; am < 4; ++am)
                #pragma unroll
                for (int bn = 0; bn < 4; ++bn)
                    acc[am][bn] = __builtin_amdgcn_mfma_f32_16x16x32_fp8_fp8(
                        af[am], bfv[bn], acc[am][bn], 0, 0, 0);
        }
        __builtin_amdgcn_sched_barrier(0);         // keep reads above barrier
        __builtin_amdgcn_s_barrier();              // all reads of buf done
        buf ^= 1;
    }

    // epilogue: C/D layout col = lane&15, row = (lane>>4)*4 + r; unscale, bf16 store
    #pragma unroll
    for (int bn = 0; bn < 4; ++bn) {
        const int col = n0 + wn + bn * 16 + laneM;
        if (col >= NT) continue;
        const float bias = biasf[col];
        #pragma unroll
        for (int am = 0; am < 4; ++am) {
            const int rbase = m0 + wm + am * 16 + u * 4;
            #pragma unroll
            for (int r = 0; r < 4; ++r) {
                float v = acc[am][bn][r] * WINV + bias;
                Zb[(size_t)(rbase + r) * NP + col] = f2bf(1.0f / (1.0f + __expf(-v)));
            }
        }
    }
}

// ---------------- per-row logits + CE partial (no atomic, no fence) ----------------
// LDS holds only the 588 ancestor z (z1|z2|z3[0:280)); z3[k] streamed global.
__global__ __launch_bounds__(256) void logits_loss(
        const u16* __restrict__ Zb, const int* __restrict__ labels,
        float* __restrict__ out, float* __restrict__ partials) {
    __shared__ float zs[NANC];             // [0,28) z1 | [28,308) z2 | [308,588) z3[0:280)
    __shared__ float red[12];
    const int b = blockIdx.x, tid = threadIdx.x;
    const u16* Zrow = Zb + (size_t)b * NP;

    const unsigned int* Zr = (const unsigned int*)Zrow;
    for (int i = tid; i < NANC / 2; i += 256) {    // 294 uints
        unsigned int v = Zr[i];
        zs[2 * i]     = bf2f(v & 0xffffu);
        zs[2 * i + 1] = bf2f(v >> 16);
    }
    __syncthreads();

    float se1 = 0.f, se2 = 0.f, se3 = 0.f;
    float4* outr4 = (float4*)(out + (size_t)b * N3);
    // z3 block starts at element 308 (uint index 154, even -> uint2-aligned)
    const uint2* Z3s = (const uint2*)(Zrow + N1 + N2);
    for (int q = tid; q < N3 / 4; q += 256) {
        const uint2 zv = Z3s[q];               // z3[4q..4q+3]
        float z3v[4] = { bf2f(zv.x & 0xffffu), bf2f(zv.x >> 16),
                         bf2f(zv.y & 0xffffu), bf2f(zv.y >> 16) };
        const int k = q * 4;
        float4 o; float* op = &o.x;
        #pragma unroll
        for (int uu = 0; uu < 4; ++uu) {
            const int kk = k + uu;
            float lg = z3v[uu] * zs[308 + kk / 10] * zs[308 + kk / 100];
            op[uu] = lg;
            se3 += __expf(lg);
        }
        outr4[q] = o;
    }
    for (int jj = tid; jj < N2; jj += 256)
        se2 += __expf(zs[N1 + jj] * zs[N1 + jj / 10]);
    if (tid < N1)
        se1 = __expf(zs[tid]);

    #pragma unroll
    for (int off = 32; off > 0; off >>= 1) {
        se1 += __shfl_down(se1, off, 64);
        se2 += __shfl_down(se2, off, 64);
        se3 += __shfl_down(se3, off, 64);
    }
    if ((tid & 63) == 0) {
        int w = tid >> 6;
        red[w] = se3; red[4 + w] = se2; red[8 + w] = se1;
    }
    __syncthreads();
    if (tid == 0) {
        float s3 = red[0] + red[1] + red[2] + red[3];
        float s2 = red[4] + red[5] + red[6] + red[7];
        float s1 = red[8] + red[9] + red[10] + red[11];
        int lab  = labels[b];
        int lab2 = lab / 10, lab1 = lab / 100;
        float l1 = zs[lab1];
        float l2 = zs[N1 + lab2] * zs[N1 + lab2 / 10];
        float l3 = bf2f((unsigned int)Zrow[N1 + N2 + lab]) * zs[308 + lab2] * zs[308 + lab1];
        partials[b] = (logf(s1) - l1) + (logf(s2) - l2) + (logf(s3) - l3);
    }
}

// ---------------- final loss reduce ----------------
__global__ __launch_bounds__(256) void final_reduce(
        const float* __restrict__ partials, float* __restrict__ out) {
    __shared__ float red[4];
    const int tid = threadIdx.x;
    float s = 0.f;
    for (int i = tid; i < BATCH; i += 256) s += partials[i];
    #pragma unroll
    for (int off = 32; off > 0; off >>= 1) s += __shfl_down(s, off, 64);
    if ((tid & 63) == 0) red[tid >> 6] = s;
    __syncthreads();
    if (tid == 0)
        out[(size_t)BATCH * N3] = (red[0] + red[1] + red[2] + red[3]) * (1.0f / BATCH);
}

extern "C" void kernel_launch(void* const* d_in, const int* in_sizes, int n_in,
                              void* d_out, int out_size, void* d_ws, size_t ws_size,
                              hipStream_t stream) {
    const float* x      = (const float*)d_in[0];
    const int*   labels = (const int*)d_in[1];
    const float* W1     = (const float*)d_in[2];
    const float* b1     = (const float*)d_in[3];
    const float* W2     = (const float*)d_in[4];
    const float* b2     = (const float*)d_in[5];
    const float* W3     = (const float*)d_in[6];
    const float* b3     = (const float*)d_in[7];
    float* out = (float*)d_out;

    char* ws = (char*)d_ws;
    u8*    Xq       = (u8*)ws;                     //  4,194,304 B  [4096][1024] fp8
    u8*    Wq       = (u8*)(ws + 4194304);         //  3,276,800 B  [3200][1024] fp8
    u16*   Zb       = (u16*)(ws + 7471104);        // 26,214,400 B  [4096][3200] bf16
    float* biasf    = (float*)(ws + 33685504);     //     12,800 B
    float* partials = (float*)(ws + 33698304);     //     16,384 B
    // total ws use: 33,714,688 B

    cast_kernel<<<(XG + WG + BG + 255) / 256, 256, 0, stream>>>(
        x, W1, W2, W3, b1, b2, b3, Xq, Wq, biasf);
    gemm_sig<<<800, 256, 0, stream>>>(Xq, Wq, biasf, Zb);
    logits_loss<<<BATCH, 256, 0, stream>>>(Zb, labels, out, partials);
    final_reduce<<<1, 256, 0, stream>>>(partials, out);
}